// Round 2
// baseline (182.316 us; speedup 1.0000x reference)
//
#include <hip/hip_runtime.h>

#define DEV __device__ __forceinline__

constexpr int D  = 2048;
constexpr int H  = 16;
constexpr int DH = 128;
constexpr int S  = 8192;
constexpr float EPS = 1e-6f;
constexpr float SCALE = 0.08838834764831845f; // DH^-0.5

typedef unsigned short ushortv8 __attribute__((ext_vector_type(8)));
typedef unsigned short ushortv4 __attribute__((ext_vector_type(4)));

DEV float bf2f(unsigned short u){ return __uint_as_float(((unsigned int)u) << 16); }
DEV unsigned short f2bf(float f){
  unsigned int x = __float_as_uint(f);
  unsigned int r = x + 0x7fffu + ((x >> 16) & 1u);
  return (unsigned short)(r >> 16);
}

// block-wide sum of two values; block = NW*64 threads
template<int NW>
DEV void block_sum2(float& a, float& b, float* buf){
  #pragma unroll
  for(int o = 32; o; o >>= 1){ a += __shfl_xor(a, o); b += __shfl_xor(b, o); }
  const int w = threadIdx.x >> 6;
  if((threadIdx.x & 63) == 0){ buf[w] = a; buf[NW + w] = b; }
  __syncthreads();
  a = buf[0]; b = buf[NW];
  #pragma unroll
  for(int i = 1; i < NW; i++){ a += buf[i]; b += buf[NW + i]; }
}

DEV float gelu(float x){
  float x3 = x * x * x;
  return 0.5f * x * (1.f + tanhf(0.7978845608028654f * (x + 0.044715f * x3)));
}

// ---------------- K1: LayerNorm all_toks -> n_all (bf16) ----------------
__global__ __launch_bounds__(256) void k_ln_all(const float* __restrict__ at,
    const float* __restrict__ g1, const float* __restrict__ b1,
    unsigned short* __restrict__ nall){
  __shared__ float buf[8];
  const int t = threadIdx.x;
  const size_t s = blockIdx.x;
  const float4* row = (const float4*)(at + s * D);
  float4 a = row[t], c = row[t + 256];
  float sum = a.x + a.y + a.z + a.w + c.x + c.y + c.z + c.w;
  float sq  = a.x*a.x + a.y*a.y + a.z*a.z + a.w*a.w
            + c.x*c.x + c.y*c.y + c.z*c.z + c.w*c.w;
  block_sum2<4>(sum, sq, buf);
  const float m = sum * (1.f / D);
  const float r = rsqrtf(sq * (1.f / D) - m * m + EPS);
  const float4* g4 = (const float4*)g1;
  const float4* b4 = (const float4*)b1;
  float4 ga = g4[t], gc = g4[t + 256], ba = b4[t], bc = b4[t + 256];
  ushortv4 oa, oc;
  oa[0] = f2bf((a.x - m) * r * ga.x + ba.x);
  oa[1] = f2bf((a.y - m) * r * ga.y + ba.y);
  oa[2] = f2bf((a.z - m) * r * ga.z + ba.z);
  oa[3] = f2bf((a.w - m) * r * ga.w + ba.w);
  oc[0] = f2bf((c.x - m) * r * gc.x + bc.x);
  oc[1] = f2bf((c.y - m) * r * gc.y + bc.y);
  oc[2] = f2bf((c.z - m) * r * gc.z + bc.z);
  oc[3] = f2bf((c.w - m) * r * gc.w + bc.w);
  ushortv4* dst = (ushortv4*)(nall + s * D);
  dst[t] = oa;
  dst[t + 256] = oc;
}

// ---------------- K2: q = LN(self_tok) @ wq + bq (single kernel) ----------------
// grid 64 blocks, each produces 32 outputs; 8 j-slices reduced via LDS.
__global__ __launch_bounds__(256) void k_q(const float* __restrict__ st,
    const float* __restrict__ g1, const float* __restrict__ b1,
    const float* __restrict__ wq, const float* __restrict__ bq,
    float* __restrict__ q){
  __shared__ float buf[8];
  __shared__ float ns[D];        // 8 KB
  __shared__ float red[8][32];
  const int t = threadIdx.x;
  const float4* st4 = (const float4*)st;
  float4 a = st4[t], c = st4[t + 256];
  float sum = a.x + a.y + a.z + a.w + c.x + c.y + c.z + c.w;
  float sq  = a.x*a.x + a.y*a.y + a.z*a.z + a.w*a.w
            + c.x*c.x + c.y*c.y + c.z*c.z + c.w*c.w;
  block_sum2<4>(sum, sq, buf);
  const float m = sum * (1.f / D);
  const float r = rsqrtf(sq * (1.f / D) - m * m + EPS);
  const float4* g4 = (const float4*)g1;
  const float4* b4 = (const float4*)b1;
  float4 ga = g4[t], gc = g4[t + 256], ba = b4[t], bc = b4[t + 256];
  float4 na, nc;
  na.x = (a.x - m) * r * ga.x + ba.x;
  na.y = (a.y - m) * r * ga.y + ba.y;
  na.z = (a.z - m) * r * ga.z + ba.z;
  na.w = (a.w - m) * r * ga.w + ba.w;
  nc.x = (c.x - m) * r * gc.x + bc.x;
  nc.y = (c.y - m) * r * gc.y + bc.y;
  nc.z = (c.z - m) * r * gc.z + bc.z;
  nc.w = (c.w - m) * r * gc.w + bc.w;
  ((float4*)ns)[t] = na;
  ((float4*)ns)[t + 256] = nc;
  __syncthreads();
  const int i = blockIdx.x * 32 + (t & 31);
  const int sl = t >> 5;
  float acc = 0.f;
  #pragma unroll 8
  for(int jj = 0; jj < 256; jj++){
    int j = sl * 256 + jj;
    acc = fmaf(ns[j], wq[(size_t)j * D + i], acc);
  }
  red[sl][t & 31] = acc;
  __syncthreads();
  if(t < 32){
    float s = bq[blockIdx.x * 32 + t];
    #pragma unroll
    for(int p = 0; p < 8; p++) s += red[p][t];
    q[blockIdx.x * 32 + t] = s;
  }
}

// ---------------- K3: wkq[j][h] = wk[j, h*128:+128] . q[h*128:+128]; qb[h]=bk.q ----------------
__global__ __launch_bounds__(256) void k_wkq(const float* __restrict__ wk,
    const float* __restrict__ bk, const float* __restrict__ q,
    float* __restrict__ wkq, float* __restrict__ qb){
  const int j = blockIdx.x, t = threadIdx.x;
  const float* src = (j < D) ? (wk + (size_t)j * D) : bk;
  const float4* s4 = (const float4*)src;
  const float4* q4 = (const float4*)q;
  float4 a = s4[2 * t], c = s4[2 * t + 1], qa = q4[2 * t], qc = q4[2 * t + 1];
  float p = a.x*qa.x + a.y*qa.y + a.z*qa.z + a.w*qa.w
          + c.x*qc.x + c.y*qc.y + c.z*qc.z + c.w*qc.w;
  #pragma unroll
  for(int o = 1; o < 16; o <<= 1) p += __shfl_xor(p, o);
  if((t & 15) == 0){
    const int h = t >> 4;
    if(j < D) wkq[j * H + h] = p;
    else      qb[h] = p;
  }
}

// ---------------- K4: scores[h][s] = SCALE*(n_all[s,:] . wkq[:,h] + qb[h]) ----------------
// grid 1024 blocks x 8 rows; thread = (h, row, j-half); broadcast-friendly LDS reads.
__global__ __launch_bounds__(256) void k_scores(const unsigned short* __restrict__ nall,
    const float* __restrict__ wkq_g, const float* __restrict__ qb,
    float* __restrict__ scores){
  __shared__ float wk_s[1024 * 16]; // 64 KB
  __shared__ float red[2][8][16];
  const int t = threadIdx.x;
  const int h = t & 15, row = (t >> 4) & 7, half = t >> 7;
  const int s0 = blockIdx.x * 8;
  float acc = 0.f;
  for(int c = 0; c < 2; c++){
    __syncthreads();
    const float4* src = (const float4*)(wkq_g + c * 1024 * H);
    float4* dst = (float4*)wk_s;
    #pragma unroll
    for(int u = 0; u < 16; u++) dst[t + 256 * u] = src[t + 256 * u];
    __syncthreads();
    const ushortv8* nv = (const ushortv8*)(nall + (size_t)(s0 + row) * D + c * 1024 + half * 512);
    #pragma unroll 4
    for(int j8 = 0; j8 < 64; j8++){
      ushortv8 A = nv[j8];
      const int jb = (half * 512 + j8 * 8) * H + h;
      #pragma unroll
      for(int k = 0; k < 8; k++)
        acc = fmaf(bf2f(A[k]), wk_s[jb + k * H], acc);
    }
  }
  red[half][row][h] = acc;
  __syncthreads();
  if(half == 0){
    float v = (acc + red[1][row][h] + qb[h]) * SCALE;
    scores[(size_t)h * S + s0 + row] = v;
  }
}

// ---------------- K5: softmax over S per head -> normalized attn ----------------
__global__ __launch_bounds__(256) void k_softmax(const float* __restrict__ scores,
    float* __restrict__ attn){
  __shared__ float mbuf[4], sbuf[4];
  const int h = blockIdx.x, t = threadIdx.x;
  const float* sc = scores + (size_t)h * S;
  float v[32];
  float mx = -3.0e38f;
  #pragma unroll
  for(int u = 0; u < 32; u++){ v[u] = sc[t + 256 * u]; mx = fmaxf(mx, v[u]); }
  #pragma unroll
  for(int o = 32; o; o >>= 1) mx = fmaxf(mx, __shfl_xor(mx, o));
  if((t & 63) == 0) mbuf[t >> 6] = mx;
  __syncthreads();
  mx = fmaxf(fmaxf(mbuf[0], mbuf[1]), fmaxf(mbuf[2], mbuf[3]));
  float sum = 0.f;
  #pragma unroll
  for(int u = 0; u < 32; u++){
    float e = __expf(v[u] - mx);
    v[u] = e;
    sum += e;
  }
  #pragma unroll
  for(int o = 32; o; o >>= 1) sum += __shfl_xor(sum, o);
  if((t & 63) == 0) sbuf[t >> 6] = sum;
  __syncthreads();
  const float inv = 1.f / (sbuf[0] + sbuf[1] + sbuf[2] + sbuf[3]);
  float* pp = attn + (size_t)h * S;
  #pragma unroll
  for(int u = 0; u < 32; u++) pp[t + 256 * u] = v[u] * inv;
}

// ---------------- K6: actx partials: part[sc][h][j] = sum_ss attn[h][s0+ss]*n[s0+ss][j] ----------------
// grid (8 jc, 32 sc), 256 rows per block
__global__ __launch_bounds__(256) void k_actx(const unsigned short* __restrict__ nall,
    const float* __restrict__ attn, float* __restrict__ part){
  __shared__ float pl[16 * 256]; // 16 KB
  const int jc = blockIdx.x, sc = blockIdx.y, t = threadIdx.x;
  const int s0 = sc * 256, j = jc * 256 + t;
  #pragma unroll
  for(int u = 0; u < 16; u++){
    int idx = t + 256 * u;
    int hh = idx >> 8, ss = idx & 255;
    pl[idx] = attn[(size_t)hh * S + s0 + ss];
  }
  __syncthreads();
  float acc[16];
  #pragma unroll
  for(int h = 0; h < 16; h++) acc[h] = 0.f;
  #pragma unroll 4
  for(int ss = 0; ss < 256; ss++){
    float v = bf2f(nall[(size_t)(s0 + ss) * D + j]);
    #pragma unroll
    for(int h = 0; h < 16; h++) acc[h] = fmaf(pl[h * 256 + ss], v, acc[h]);
  }
  #pragma unroll
  for(int h = 0; h < 16; h++) part[((size_t)sc * 16 + h) * D + j] = acc[h];
}

// ---------------- K7: wv partials with inline actx reduction ----------------
// grid (16 h, 8 jc); part_wv[jc][i] = sum_{j in slice} a_ctx[h][j]*wv[j][i]
__global__ __launch_bounds__(256) void k_wv(const float* __restrict__ part,
    const float* __restrict__ wv, float* __restrict__ part_wv){
  __shared__ float as[256];
  __shared__ float red2[2][128];
  const int h = blockIdx.x, jc = blockIdx.y, t = threadIdx.x;
  const int j0 = jc * 256;
  float s = 0.f;
  #pragma unroll 8
  for(int sc = 0; sc < 32; sc++) s += part[((size_t)sc * 16 + h) * D + j0 + t];
  as[t] = s;
  __syncthreads();
  const int i = h * DH + (t & 127), hf = t >> 7;
  float acc = 0.f;
  #pragma unroll 8
  for(int jj = 0; jj < 128; jj++){
    int jl = hf * 128 + jj;
    acc = fmaf(as[jl], wv[(size_t)(j0 + jl) * D + i], acc);
  }
  red2[hf][t & 127] = acc;
  __syncthreads();
  if(t < 128) part_wv[(size_t)jc * D + h * DH + t] = red2[0][t] + red2[1][t];
}

// ---------------- K8: wo partials with inline wv reduction (+bv) ----------------
// grid (8 ic, 16 jc)
__global__ __launch_bounds__(256) void k_wo(const float* __restrict__ part_wv,
    const float* __restrict__ bv, const float* __restrict__ wo,
    float* __restrict__ part_wo){
  __shared__ float oa[128];
  const int ic = blockIdx.x, jc = blockIdx.y, t = threadIdx.x;
  if(t < 128){
    int j = jc * 128 + t;
    float s = bv[j];
    #pragma unroll
    for(int p = 0; p < 8; p++) s += part_wv[(size_t)p * D + j];
    oa[t] = s;
  }
  __syncthreads();
  const int i = ic * 256 + t;
  float acc = 0.f;
  #pragma unroll 8
  for(int jj = 0; jj < 128; jj++)
    acc = fmaf(oa[jj], wo[(size_t)(jc * 128 + jj) * D + i], acc);
  part_wo[(size_t)jc * D + i] = acc;
}

// ---------------- K9: x = self_tok + bo + sum(parts); x2 = LN(x)*g2+b2 ----------------
__global__ __launch_bounds__(1024) void k_x_ln2(const float* __restrict__ self_tok,
    const float* __restrict__ bo, const float* __restrict__ part_wo,
    const float* __restrict__ g2, const float* __restrict__ b2,
    float* __restrict__ x, float* __restrict__ x2){
  __shared__ float buf[32];
  const int t = threadIdx.x;
  float xv0, xv1;
  {
    float s = self_tok[t] + bo[t];
    #pragma unroll
    for(int jc = 0; jc < 16; jc++) s += part_wo[(size_t)jc * D + t];
    xv0 = s; x[t] = s;
  }
  {
    const int i = t + 1024;
    float s = self_tok[i] + bo[i];
    #pragma unroll
    for(int jc = 0; jc < 16; jc++) s += part_wo[(size_t)jc * D + i];
    xv1 = s; x[i] = s;
  }
  float sum = xv0 + xv1, sq = xv0 * xv0 + xv1 * xv1;
  block_sum2<16>(sum, sq, buf);
  const float m = sum * (1.f / D);
  const float r = rsqrtf(sq * (1.f / D) - m * m + EPS);
  x2[t]        = (xv0 - m) * r * g2[t] + b2[t];
  x2[t + 1024] = (xv1 - m) * r * g2[t + 1024] + b2[t + 1024];
}

// ---------------- K10: f1 partials: part_f1[jc][o] = sum_{j slice} x2[j]*w1[j][o] ----------------
// grid (32 oc, 16 jc)
__global__ __launch_bounds__(256) void k_f1(const float* __restrict__ x2,
    const float* __restrict__ w1, float* __restrict__ part_f1){
  __shared__ float xs[128];
  const int oc = blockIdx.x, jc = blockIdx.y, t = threadIdx.x;
  if(t < 128) xs[t] = x2[jc * 128 + t];
  __syncthreads();
  const int o = oc * 256 + t;
  float acc = 0.f;
  #pragma unroll 8
  for(int jj = 0; jj < 128; jj++)
    acc = fmaf(xs[jj], w1[(size_t)(jc * 128 + jj) * (4 * D) + o], acc);
  part_f1[(size_t)jc * (4 * D) + o] = acc;
}

// ---------------- K11: f2 partials with inline f1-reduce + gelu ----------------
// grid (8 ic, 64 jc); j indexes the 8192-dim hidden
__global__ __launch_bounds__(256) void k_f2(const float* __restrict__ part_f1,
    const float* __restrict__ b_f1, const float* __restrict__ w2,
    float* __restrict__ part_f2){
  __shared__ float hs[128];
  const int ic = blockIdx.x, jc = blockIdx.y, t = threadIdx.x;
  if(t < 128){
    int j = jc * 128 + t;
    float s = b_f1[j];
    #pragma unroll
    for(int p = 0; p < 16; p++) s += part_f1[(size_t)p * (4 * D) + j];
    hs[t] = gelu(s);
  }
  __syncthreads();
  const int i = ic * 256 + t;
  float acc = 0.f;
  #pragma unroll 8
  for(int jj = 0; jj < 128; jj++)
    acc = fmaf(hs[jj], w2[(size_t)(jc * 128 + jj) * D + i], acc);
  part_f2[(size_t)jc * D + i] = acc;
}

// ---------------- K12: out = x + b_f2 + sum(part_f2) ----------------
__global__ __launch_bounds__(256) void k_final(const float* __restrict__ part_f2,
    const float* __restrict__ x, const float* __restrict__ b_f2,
    float* __restrict__ out){
  const int i = blockIdx.x * 256 + threadIdx.x;
  float s = x[i] + b_f2[i];
  #pragma unroll 8
  for(int jc = 0; jc < 64; jc++) s += part_f2[(size_t)jc * D + i];
  out[i] = s;
}

extern "C" void kernel_launch(void* const* d_in, const int* in_sizes, int n_in,
                              void* d_out, int out_size, void* d_ws, size_t ws_size,
                              hipStream_t stream){
  const float* self_tok = (const float*)d_in[0];
  const float* all_toks = (const float*)d_in[1];
  const float* wq = (const float*)d_in[2];
  const float* bq = (const float*)d_in[3];
  const float* wk = (const float*)d_in[4];
  const float* bk = (const float*)d_in[5];
  const float* wv = (const float*)d_in[6];
  const float* bv = (const float*)d_in[7];
  const float* wo = (const float*)d_in[8];
  const float* bo = (const float*)d_in[9];
  const float* g1 = (const float*)d_in[10];
  const float* b1 = (const float*)d_in[11];
  const float* g2 = (const float*)d_in[12];
  const float* b2 = (const float*)d_in[13];
  const float* w1 = (const float*)d_in[14];
  const float* b_f1 = (const float*)d_in[15];
  const float* w2 = (const float*)d_in[16];
  const float* b_f2 = (const float*)d_in[17];
  float* out = (float*)d_out;

  char* wptr = (char*)d_ws;
  auto alloc = [&](size_t bytes) -> void* {
    void* p = (void*)wptr;
    wptr += (bytes + 255) & ~(size_t)255;
    return p;
  };
  unsigned short* n_all = (unsigned short*)alloc((size_t)S * D * 2);
  float* scores    = (float*)alloc((size_t)H * S * 4);
  float* attn      = (float*)alloc((size_t)H * S * 4);
  float* q         = (float*)alloc((size_t)D * 4);
  float* qb        = (float*)alloc(64);
  float* wkq       = (float*)alloc((size_t)D * H * 4);
  float* part_actx = (float*)alloc((size_t)32 * H * D * 4);
  float* part_wv   = (float*)alloc((size_t)8 * D * 4);
  float* part_wo   = (float*)alloc((size_t)16 * D * 4);
  float* xbuf      = (float*)alloc((size_t)D * 4);
  float* x2        = (float*)alloc((size_t)D * 4);
  float* part_f1   = (float*)alloc((size_t)16 * 4 * D * 4);
  float* part_f2   = (float*)alloc((size_t)64 * D * 4);

  // q chain (independent of all_toks path)
  k_q<<<64, 256, 0, stream>>>(self_tok, g1, b1, wq, bq, q);
  k_wkq<<<D + 1, 256, 0, stream>>>(wk, bk, q, wkq, qb);
  // attention path
  k_ln_all<<<S, 256, 0, stream>>>(all_toks, g1, b1, n_all);
  k_scores<<<S / 8, 256, 0, stream>>>(n_all, wkq, qb, scores);
  k_softmax<<<H, 256, 0, stream>>>(scores, attn);
  k_actx<<<dim3(8, 32), 256, 0, stream>>>(n_all, attn, part_actx);
  k_wv<<<dim3(16, 8), 256, 0, stream>>>(part_actx, wv, part_wv);
  k_wo<<<dim3(8, 16), 256, 0, stream>>>(part_wv, bv, wo, part_wo);
  k_x_ln2<<<1, 1024, 0, stream>>>(self_tok, bo, part_wo, g2, b2, xbuf, x2);
  // ffn
  k_f1<<<dim3(32, 16), 256, 0, stream>>>(x2, w1, part_f1);
  k_f2<<<dim3(8, 64), 256, 0, stream>>>(part_f1, b_f1, w2, part_f2);
  k_final<<<8, 256, 0, stream>>>(part_f2, xbuf, b_f2, out);
}